// Round 1
// baseline (465.592 us; speedup 1.0000x reference)
//
#include <hip/hip_runtime.h>
#include <math.h>

typedef unsigned int u32;
typedef float nfloat4 __attribute__((ext_vector_type(4)));

// ---------------------------------------------------------------------------
// Exact 0.99-quantile of |x| via 2-level radix select on float bit patterns.
// R3 structure (287.5us champion) + R7: SPECULATIVE CANDIDATE CAPTURE.
// K2's full 134MB re-read existed only to find the ~0.65% of elements in the
// level-1 winning bucket B1. K1 now also compacts all elements with top-11
// bits in [1025,1027] (|x| in [2.25,3.0) -- covers the 0.99 quantile 2.576
// +/- 0.002 with >30 sigma margin) into per-block ws segments via wave
// ballot + per-BLOCK counters (single global counter would be ~400K
// same-address atomics -- serialization trap; R4/R6 showed fences/tickets
// regress). K2 -> resolve_low: rederive B1 from L2-hot g1; if B1 in window
// and no segment overflow, histogram the ~2.9MB capture list instead of
// 134MB; else (any other input, or ws too small -> host forces) fall back
// to the original full scan IN THE SAME KERNEL -- exact for all inputs, no
// extra dispatch, no cross-block sync. All visibility via kernel boundaries.
//  K1 hist_top    : 2048-bin hist of bits[30:20], 8-replica LDS -> g1
//                   + capture |x| in [2.25,3.0) -> gcnt[b], cap[b*CAPB..]
//  K2 resolve_low : prologue re-scans g1 -> B1; valid -> hist low 20 bits of
//                   captured elems with top==B1 -> h2 ; invalid -> full scan
//  K3 chunk_reduce: 1024 blocks sum h2 chunks -> cs[1024] (plain stores)
//  K4 quantize    : prologue re-scans g1 -> (B1,k1), cs -> (chunk,k2),
//                   h2[chunk] -> exact bits -> scale; then fake-quantize
// ws layout (u32): [0..2047] g1 | [2048..3071] cs | [3584..4095] gcnt |
//                  [4096..4096+1M) h2 | [CAP .. CAP+512*CAPB) capture
// ---------------------------------------------------------------------------

#define G1 0
#define CS 2048
#define GCNT 3584
#define H2 4096
#define CAP (4096 + (1 << 20))
#define CAPB 4096u                 // per-block capture capacity (expected ~1424)
#define NBLK1 512                  // hist_top / resolve_low grid
#define ZERO_U32 (4096 + (1 << 20))
#define NEED_U32 ((size_t)CAP + (size_t)NBLK1 * CAPB)
// capture window: top-11 bits in [1025,1027] <=> |x| in [2.25, 3.0)
#define WIN_LO 1025u
#define WIN_HI 1027u

__global__ __launch_bounds__(1024) void hist_top(const u32* __restrict__ x,
                                                 u32* __restrict__ ws,
                                                 long long n, int do_cap) {
  u32* g1 = ws + G1;
  u32* gcnt_b = ws + GCNT + blockIdx.x;
  u32* cap_b = ws + CAP + (size_t)blockIdx.x * CAPB;
  __shared__ u32 h[2048 * 8];  // 8 interleaved replicas, 64 KB
  const int t = threadIdx.x;
  const int lane = t & 63;
  for (int i = t; i < 2048 * 8; i += 1024) h[i] = 0;
  __syncthreads();

  const u32 r = (u32)(t & 7);
  const long long n4 = n >> 2;
  const long long stride = (long long)gridDim.x * 1024;
  const uint4* x4 = (const uint4*)x;

  // wave-aggregated append: ballot -> one per-block atomic per wave-step
#define CAPTURE(a)                                                         \
  do {                                                                     \
    const bool take_ = do_cap && (((a) >> 20) - WIN_LO) <= (WIN_HI - WIN_LO); \
    const unsigned long long m_ = __ballot(take_);                         \
    if (m_) {                                                              \
      const u32 pos_ = (u32)__builtin_popcountll(m_ & ((1ull << lane) - 1ull)); \
      const int ldr_ = (int)__builtin_ctzll(m_);                           \
      u32 base_ = 0;                                                       \
      if (lane == ldr_)                                                    \
        base_ = atomicAdd(gcnt_b, (u32)__builtin_popcountll(m_));          \
      base_ = __shfl(base_, ldr_, 64);                                     \
      const u32 idx_ = base_ + pos_;                                       \
      if (take_ && idx_ < CAPB) cap_b[idx_] = (a);                         \
    }                                                                      \
  } while (0)

  for (long long i = (long long)blockIdx.x * 1024 + t; i < n4; i += stride) {
    uint4 v = x4[i];
    const u32 ax = v.x & 0x7fffffffu;
    const u32 ay = v.y & 0x7fffffffu;
    const u32 az = v.z & 0x7fffffffu;
    const u32 aw = v.w & 0x7fffffffu;
    atomicAdd(&h[((ax >> 20) << 3) + r], 1u);
    atomicAdd(&h[((ay >> 20) << 3) + r], 1u);
    atomicAdd(&h[((az >> 20) << 3) + r], 1u);
    atomicAdd(&h[((aw >> 20) << 3) + r], 1u);
    CAPTURE(ax);
    CAPTURE(ay);
    CAPTURE(az);
    CAPTURE(aw);
  }
  for (long long i = (n4 << 2) + (long long)blockIdx.x * 1024 + t; i < n;
       i += stride) {
    const u32 a = x[i] & 0x7fffffffu;
    atomicAdd(&h[((a >> 20) << 3) + r], 1u);
    if (do_cap && ((a >> 20) - WIN_LO) <= (WIN_HI - WIN_LO)) {
      const u32 p = atomicAdd(gcnt_b, 1u);
      if (p < CAPB) cap_b[p] = a;
    }
  }
#undef CAPTURE
  __syncthreads();
  for (int i = t; i < 2048; i += 1024) {
    u32 c = 0;
#pragma unroll
    for (int j = 0; j < 8; ++j) c += h[(i << 3) + j];
    if (c) atomicAdd(&g1[i], c);
  }
}

// Replaces hist_low. Valid capture -> histogram ~2.9MB capture list.
// Invalid (other input distribution / overflow / host-forced) -> full scan.
__global__ __launch_bounds__(256) void resolve_low(const u32* __restrict__ x,
                                                   u32* __restrict__ ws,
                                                   long long n, u32 k,
                                                   int force_full) {
  __shared__ u32 s[256];
  __shared__ u32 rB1;
  __shared__ int bad;
  const u32* g1 = ws + G1;
  const u32* gcnt = ws + GCNT;
  const u32* cap = ws + CAP;
  u32* h2 = ws + H2;
  const int t = threadIdx.x;
  if (t == 0) bad = force_full;

  // prologue: redundant scan of L2-hot g1 (8 KB) -> B1 (same as quantize A)
  u32 c[8], sum = 0;
#pragma unroll
  for (int j = 0; j < 8; ++j) { c[j] = g1[t * 8 + j]; sum += c[j]; }
  s[t] = sum;
  __syncthreads();
  for (int off = 1; off < 256; off <<= 1) {
    u32 add = (t >= off) ? s[t - off] : 0u;
    __syncthreads();
    s[t] += add;
    __syncthreads();
  }
  u32 ex = s[t] - sum;
#pragma unroll
  for (int j = 0; j < 8; ++j) {
    if (k >= ex && k < ex + c[j]) rB1 = (u32)(t * 8 + j);
    ex += c[j];
  }
  // per-block segment overflow check (gcnt counts ALL takes incl. unstored)
  for (int i = t; i < NBLK1; i += 256)
    if (gcnt[i] > CAPB) bad = 1;  // benign race, all write 1
  __syncthreads();
  const u32 B1 = rB1;
  if (t == 0 && (B1 < WIN_LO || B1 > WIN_HI)) bad = 1;
  __syncthreads();

  if (!bad) {
    // fast path: every B1-element is in the capture list exactly once
    const u32 cnt = gcnt[blockIdx.x];
    const u32* seg = cap + (size_t)blockIdx.x * CAPB;
    for (u32 i = (u32)t; i < cnt; i += 256) {
      const u32 a = seg[i];
      if ((a >> 20) == B1) atomicAdd(&h2[a & 0xFFFFFu], 1u);
    }
  } else {
    // exact fallback: original full scan (correct for any input)
    const long long n4 = n >> 2;
    const long long stride = (long long)gridDim.x * 256;
    const uint4* x4 = (const uint4*)x;
    for (long long i = (long long)blockIdx.x * 256 + t; i < n4; i += stride) {
      uint4 v = x4[i];
      u32 a;
      a = v.x & 0x7fffffffu; if ((a >> 20) == B1) atomicAdd(&h2[a & 0xFFFFFu], 1u);
      a = v.y & 0x7fffffffu; if ((a >> 20) == B1) atomicAdd(&h2[a & 0xFFFFFu], 1u);
      a = v.z & 0x7fffffffu; if ((a >> 20) == B1) atomicAdd(&h2[a & 0xFFFFFu], 1u);
      a = v.w & 0x7fffffffu; if ((a >> 20) == B1) atomicAdd(&h2[a & 0xFFFFFu], 1u);
    }
    for (long long i = (n4 << 2) + (long long)blockIdx.x * 256 + t; i < n;
         i += stride) {
      const u32 a = x[i] & 0x7fffffffu;
      if ((a >> 20) == B1) atomicAdd(&h2[a & 0xFFFFFu], 1u);
    }
  }
}

// 1024 blocks: block b sums h2[b*1024 .. b*1024+1024) -> cs[b] (plain store)
__global__ __launch_bounds__(256) void chunk_reduce(u32* __restrict__ ws) {
  const u32* h2 = ws + H2;
  u32* cs = ws + CS;
  const int t = threadIdx.x;
  uint4 v = ((const uint4*)(h2 + (size_t)blockIdx.x * 1024))[t];
  u32 sum = v.x + v.y + v.z + v.w;
#pragma unroll
  for (int off = 32; off > 0; off >>= 1) sum += __shfl_down(sum, off, 64);
  __shared__ u32 w[4];
  if ((t & 63) == 0) w[t >> 6] = sum;
  __syncthreads();
  if (t == 0) cs[blockIdx.x] = w[0] + w[1] + w[2] + w[3];
}

__global__ __launch_bounds__(256) void quantize(const float* __restrict__ x,
                                                float* __restrict__ out,
                                                const u32* __restrict__ ws,
                                                const float* __restrict__ gamma,
                                                long long n, u32 k) {
  // --- prologue: every block redundantly derives scale from L2-hot hists ---
  __shared__ u32 s[256];
  __shared__ u32 r0, r1;
  __shared__ float fscale;
  const u32* g1 = ws + G1;
  const u32* cs = ws + CS;
  const u32* h2 = ws + H2;
  const int t = threadIdx.x;

  // scan A: g1 (2048 bins, 8/thread) -> B1, k1
  u32 B1, k1;
  {
    u32 c[8], sum = 0;
#pragma unroll
    for (int j = 0; j < 8; ++j) { c[j] = g1[t * 8 + j]; sum += c[j]; }
    s[t] = sum;
    __syncthreads();
    for (int off = 1; off < 256; off <<= 1) {
      u32 add = (t >= off) ? s[t - off] : 0u;
      __syncthreads();
      s[t] += add;
      __syncthreads();
    }
    u32 ex = s[t] - sum;
#pragma unroll
    for (int j = 0; j < 8; ++j) {
      if (k >= ex && k < ex + c[j]) { r0 = (u32)(t * 8 + j); r1 = k - ex; }
      ex += c[j];
    }
    __syncthreads();
    B1 = r0; k1 = r1;
  }
  // scan B: cs (1024 chunk sums, 4/thread) -> chunk, k2
  u32 chunk, k2;
  {
    u32 c[4], sum = 0;
#pragma unroll
    for (int j = 0; j < 4; ++j) { c[j] = cs[t * 4 + j]; sum += c[j]; }
    __syncthreads();  // protect r0/r1 reads above before rewrite below
    s[t] = sum;
    __syncthreads();
    for (int off = 1; off < 256; off <<= 1) {
      u32 add = (t >= off) ? s[t - off] : 0u;
      __syncthreads();
      s[t] += add;
      __syncthreads();
    }
    u32 ex = s[t] - sum;
#pragma unroll
    for (int j = 0; j < 4; ++j) {
      if (k1 >= ex && k1 < ex + c[j]) { r0 = (u32)(t * 4 + j); r1 = k1 - ex; }
      ex += c[j];
    }
    __syncthreads();
    chunk = r0; k2 = r1;
  }
  // scan C: h2[chunk*1024 ..] (1024 bins, 4/thread) -> exact bits -> scale
  {
    u32 c[4], sum = 0;
#pragma unroll
    for (int j = 0; j < 4; ++j) {
      c[j] = h2[(size_t)chunk * 1024 + t * 4 + j];
      sum += c[j];
    }
    __syncthreads();
    s[t] = sum;
    __syncthreads();
    for (int off = 1; off < 256; off <<= 1) {
      u32 add = (t >= off) ? s[t - off] : 0u;
      __syncthreads();
      s[t] += add;
      __syncthreads();
    }
    u32 ex = s[t] - sum;
#pragma unroll
    for (int j = 0; j < 4; ++j) {
      if (k2 >= ex && k2 < ex + c[j]) {
        const u32 bits = (B1 << 20) | (chunk * 1024u + (u32)(t * 4 + j));
        const float q = __uint_as_float(bits);
        float gm = gamma[0];
        gm = fminf(fmaxf(gm, 0.1f), 10.0f);
        fscale = (q / 127.0f) * gm;
      }
      ex += c[j];
    }
    __syncthreads();
  }
  const float scale = fscale;

  // --- hot loop: identical to R3 ---
  const long long n4 = n >> 2;
  const long long stride = (long long)gridDim.x * 256;
  const float4* x4 = (const float4*)x;
  nfloat4* o4 = (nfloat4*)out;
  for (long long i = (long long)blockIdx.x * 256 + t; i < n4; i += stride) {
    float4 v = x4[i];
    nfloat4 o;
    o.x = fminf(fmaxf(rintf(v.x / scale), -128.0f), 127.0f) * scale;
    o.y = fminf(fmaxf(rintf(v.y / scale), -128.0f), 127.0f) * scale;
    o.z = fminf(fmaxf(rintf(v.z / scale), -128.0f), 127.0f) * scale;
    o.w = fminf(fmaxf(rintf(v.w / scale), -128.0f), 127.0f) * scale;
    __builtin_nontemporal_store(o, &o4[i]);
  }
  for (long long i = (n4 << 2) + (long long)blockIdx.x * 256 + t; i < n;
       i += stride) {
    float v = x[i];
    out[i] = fminf(fmaxf(rintf(v / scale), -128.0f), 127.0f) * scale;
  }
}

extern "C" void kernel_launch(void* const* d_in, const int* in_sizes, int n_in,
                              void* d_out, int out_size, void* d_ws,
                              size_t ws_size, hipStream_t stream) {
  const u32* xbits = (const u32*)d_in[0];
  const float* gamma = (const float*)d_in[1];
  const long long n = (long long)in_sizes[0];
  u32* ws = (u32*)d_ws;

  const u32 k = (u32)llround(0.99 * (double)n);
  // capture machinery needs ~12.6 MB of ws; if unavailable, force the exact
  // full-scan path (identical to R3 behavior)
  const int cap_ok = (ws_size >= NEED_U32 * sizeof(u32)) ? 1 : 0;

  (void)hipMemsetAsync(ws, 0, (size_t)ZERO_U32 * sizeof(u32), stream);
  hist_top<<<NBLK1, 1024, 0, stream>>>(xbits, ws, n, cap_ok);
  resolve_low<<<NBLK1, 256, 0, stream>>>(xbits, ws, n, k, cap_ok ? 0 : 1);
  chunk_reduce<<<1024, 256, 0, stream>>>(ws);
  quantize<<<2048, 256, 0, stream>>>((const float*)d_in[0], (float*)d_out, ws,
                                     gamma, n, k);
}

// Round 2
// 356.084 us; speedup vs baseline: 1.3075x; 1.3075x over previous
//
#include <hip/hip_runtime.h>
#include <math.h>

typedef unsigned int u32;
typedef float nfloat4 __attribute__((ext_vector_type(4)));

// ---------------------------------------------------------------------------
// Exact 0.99-quantile of |x| via windowed candidate capture + exact fallback.
// R8: K1 no longer builds the 2048-bin histogram (33.5M LDS atomics was the
// bottleneck: 0.73 atomics/cyc/CU, 1.7 TB/s effective). Exact selection only
// needs: count(|x|<2.25), per-bucket counts of the 3 window buckets
// [2.25,3.0) (register increments), and the captured window elements
// (~2.2% of data). R7's ballot+global-atomic capture serialized the wave
// (244us, VALU 7.7%); now: rare per-lane LDS-counter atomic + direct global
// store -- no cross-lane ops in the hot loop. Fallback path (any other
// input distribution, capture overflow, or small ws) is EXACT: resolve
// detects it deterministically BEFORE writing h2, builds the full 2048-bin
// g1 itself, and always-enqueued fallback_low (no-op ~2us on fast path)
// redoes the original full scan. All producer->consumer visibility via
// kernel boundaries only (R4/R6: fences/tickets regress).
//  K1 scan_top    : stream x; reg-count below/window buckets -> bc[4];
//                   capture window elems -> gcnt[b], cap[b*CAPB..]
//  K2 resolve     : fast: derive B1 from bc -> hist low 20 bits of captured
//                   B1-elems -> h2. bad: set FLAG, full 2048-bin hist -> g1
//  K2b fallback_low: FLAG? original full-scan hist_low : exit
//  K3 chunk_reduce: 1024 blocks sum h2 chunks -> cs[1024]
//  K4 quantize    : prologue: FLAG? scan g1 : derive (B1,k1) from bc;
//                   then cs -> (chunk,k2), h2[chunk] -> bits -> scale
// ws layout (u32): [0..2047] g1 | [2048..3071] cs | [3072..3075] bc |
//   [3076] FLAG | [4096..6143] gcnt | [8192..8192+1M) h2 | [CAP..) capture
// ---------------------------------------------------------------------------

#define G1 0
#define CS 2048
#define BC 3072
#define FLAG 3076
#define GCNT 4096
#define H2 8192
#define CAP (8192 + (1 << 20))
#define CAPB 1024u   // per-block capture capacity (expected ~356, sd ~19)
#define NBLK1 2048   // scan_top / resolve grid
#define ZERO_U32 (8192 + (1 << 20))
#define NEED_U32 ((size_t)CAP + (size_t)NBLK1 * CAPB)
// capture window: top-11 bits in [1025,1027] <=> |x| in [2.25, 3.0);
// 0.99-quantile of N(0,1) data = 2.576 +/- 0.002 -- covered with huge margin
#define WIN_LO 1025u
#define WIN_HI 1027u
#define LOBITS (WIN_LO << 20)
#define SPANBITS ((WIN_HI - WIN_LO + 1u) << 20)

__global__ __launch_bounds__(256) void scan_top(const u32* __restrict__ x,
                                                u32* __restrict__ ws,
                                                long long n, int do_cap) {
  u32* bc = ws + BC;
  u32* cap_b = ws + CAP + (size_t)blockIdx.x * CAPB;
  __shared__ u32 lcnt;
  __shared__ u32 red[4][4];
  const int t = threadIdx.x;
  if (t == 0) lcnt = 0;
  __syncthreads();

  u32 bel = 0, w0 = 0, w2 = 0, tk = 0;

  const long long n4 = n >> 2;
  const long long stride = (long long)gridDim.x * 256;
  const uint4* x4 = (const uint4*)x;

#define PROC(raw)                                     \
  do {                                                \
    const u32 a_ = (raw) & 0x7fffffffu;               \
    bel += (a_ < LOBITS) ? 1u : 0u;                   \
    const u32 d_ = a_ - LOBITS;                       \
    if (d_ < SPANBITS) {                              \
      tk += 1u;                                       \
      w0 += (d_ < (1u << 20)) ? 1u : 0u;              \
      w2 += (d_ >= (2u << 20)) ? 1u : 0u;             \
      if (do_cap) {                                   \
        const u32 p_ = atomicAdd(&lcnt, 1u);          \
        if (p_ < CAPB) cap_b[p_] = a_;                \
      }                                               \
    }                                                 \
  } while (0)

  for (long long i = (long long)blockIdx.x * 256 + t; i < n4; i += stride) {
    uint4 v = x4[i];
    PROC(v.x);
    PROC(v.y);
    PROC(v.z);
    PROC(v.w);
  }
  for (long long i = (n4 << 2) + (long long)blockIdx.x * 256 + t; i < n;
       i += stride)
    PROC(x[i]);
#undef PROC

#pragma unroll
  for (int off = 32; off > 0; off >>= 1) {
    bel += __shfl_down(bel, off, 64);
    w0 += __shfl_down(w0, off, 64);
    w2 += __shfl_down(w2, off, 64);
    tk += __shfl_down(tk, off, 64);
  }
  if ((t & 63) == 0) {
    const int w = t >> 6;
    red[w][0] = bel;
    red[w][1] = w0;
    red[w][2] = w2;
    red[w][3] = tk;
  }
  __syncthreads();
  if (t == 0) {
    u32 B = 0, W0 = 0, W2 = 0, TK = 0;
#pragma unroll
    for (int w = 0; w < 4; ++w) {
      B += red[w][0];
      W0 += red[w][1];
      W2 += red[w][2];
      TK += red[w][3];
    }
    if (B) atomicAdd(&bc[0], B);
    if (W0) atomicAdd(&bc[1], W0);
    const u32 W1 = TK - W0 - W2;
    if (W1) atomicAdd(&bc[2], W1);
    if (W2) atomicAdd(&bc[3], W2);
    ws[GCNT + blockIdx.x] = lcnt;
  }
}

// Fast path: histogram the ~2.9MB capture list (B1-bucket elems) into h2.
// Bad path (deterministic, decided BEFORE any h2 write): set FLAG and build
// the full 2048-bin g1 so fallback_low/quantize can run the exact R3 path.
__global__ __launch_bounds__(256) void resolve(const u32* __restrict__ x,
                                               u32* __restrict__ ws,
                                               long long n, u32 k,
                                               int force_full) {
  __shared__ int bad;
  __shared__ u32 sB1;
  __shared__ u32 h[2048 * 2];  // 16 KB, fallback-only use
  const u32* bc = ws + BC;
  const u32* gcnt = ws + GCNT;
  const u32* cap = ws + CAP;
  u32* g1 = ws + G1;
  u32* h2 = ws + H2;
  const int t = threadIdx.x;
  if (t == 0) bad = force_full;
  __syncthreads();

  // deterministic validity check (every block computes the same answer)
  u32 ov = 0;
  for (int i = t; i < NBLK1; i += 256) ov |= (gcnt[i] > CAPB) ? 1u : 0u;
  if (ov) bad = 1;  // benign race: only 1s written after the sync above
  if (t == 0) {
    const u32 below = bc[0], W0 = bc[1], W1 = bc[2], W2 = bc[3];
    if (k < below || k >= below + W0 + W1 + W2)
      bad = 1;
    else {
      const u32 sub = k - below;
      sB1 = (sub < W0) ? WIN_LO : ((sub < W0 + W1) ? WIN_LO + 1u : WIN_LO + 2u);
    }
  }
  __syncthreads();

  if (!bad) {
    const u32 B1 = sB1;
    const u32 cnt = min(gcnt[blockIdx.x], CAPB);
    const u32* seg = cap + (size_t)blockIdx.x * CAPB;
    for (u32 i = (u32)t; i < cnt; i += 256) {
      const u32 a = seg[i];
      if ((a >> 20) == B1) atomicAdd(&h2[a & 0xFFFFFu], 1u);
    }
  } else {
    if (t == 0 && blockIdx.x == 0) ws[FLAG] = 1u;
    // exact fallback: full 2048-bin top histogram -> g1 (2 LDS replicas;
    // correctness path, speed irrelevant)
    for (int i = t; i < 2048 * 2; i += 256) h[i] = 0;
    __syncthreads();
    const u32 r = (u32)(t & 1);
    const long long n4 = n >> 2;
    const long long stride = (long long)gridDim.x * 256;
    const uint4* x4 = (const uint4*)x;
    for (long long i = (long long)blockIdx.x * 256 + t; i < n4; i += stride) {
      uint4 v = x4[i];
      atomicAdd(&h[(((v.x & 0x7fffffffu) >> 20) << 1) + r], 1u);
      atomicAdd(&h[(((v.y & 0x7fffffffu) >> 20) << 1) + r], 1u);
      atomicAdd(&h[(((v.z & 0x7fffffffu) >> 20) << 1) + r], 1u);
      atomicAdd(&h[(((v.w & 0x7fffffffu) >> 20) << 1) + r], 1u);
    }
    for (long long i = (n4 << 2) + (long long)blockIdx.x * 256 + t; i < n;
         i += stride)
      atomicAdd(&h[(((x[i] & 0x7fffffffu) >> 20) << 1) + r], 1u);
    __syncthreads();
    for (int i = t; i < 2048; i += 256) {
      const u32 c = h[2 * i] + h[2 * i + 1];
      if (c) atomicAdd(&g1[i], c);
    }
  }
}

// Always enqueued; no-op unless FLAG (exact fallback: original hist_low).
__global__ __launch_bounds__(1024) void fallback_low(const u32* __restrict__ x,
                                                     u32* __restrict__ ws,
                                                     long long n, u32 k) {
  __shared__ u32 s[1024];
  __shared__ u32 resB1;
  if (ws[FLAG] == 0u) return;  // uniform: all threads see the same value

  const u32* g1 = ws + G1;
  u32* h2 = ws + H2;
  const int t = threadIdx.x;
  {
    const uint2 c2 = ((const uint2*)g1)[t];
    const u32 sum = c2.x + c2.y;
    s[t] = sum;
    __syncthreads();
    for (int off = 1; off < 1024; off <<= 1) {
      u32 add = (t >= off) ? s[t - off] : 0u;
      __syncthreads();
      s[t] += add;
      __syncthreads();
    }
    u32 ex = s[t] - sum;
    if (k >= ex && k < ex + c2.x) resB1 = 2 * t;
    ex += c2.x;
    if (k >= ex && k < ex + c2.y) resB1 = 2 * t + 1;
    __syncthreads();
  }
  const u32 B1 = resB1;

  const long long n4 = n >> 2;
  const long long stride = (long long)gridDim.x * 1024;
  const uint4* x4 = (const uint4*)x;
  for (long long i = (long long)blockIdx.x * 1024 + t; i < n4; i += stride) {
    uint4 v = x4[i];
    u32 a;
    a = v.x & 0x7fffffffu; if ((a >> 20) == B1) atomicAdd(&h2[a & 0xFFFFFu], 1u);
    a = v.y & 0x7fffffffu; if ((a >> 20) == B1) atomicAdd(&h2[a & 0xFFFFFu], 1u);
    a = v.z & 0x7fffffffu; if ((a >> 20) == B1) atomicAdd(&h2[a & 0xFFFFFu], 1u);
    a = v.w & 0x7fffffffu; if ((a >> 20) == B1) atomicAdd(&h2[a & 0xFFFFFu], 1u);
  }
  for (long long i = (n4 << 2) + (long long)blockIdx.x * 1024 + t; i < n;
       i += stride) {
    const u32 a = x[i] & 0x7fffffffu;
    if ((a >> 20) == B1) atomicAdd(&h2[a & 0xFFFFFu], 1u);
  }
}

// 1024 blocks: block b sums h2[b*1024 .. b*1024+1024) -> cs[b] (plain store)
__global__ __launch_bounds__(256) void chunk_reduce(u32* __restrict__ ws) {
  const u32* h2 = ws + H2;
  u32* cs = ws + CS;
  const int t = threadIdx.x;
  uint4 v = ((const uint4*)(h2 + (size_t)blockIdx.x * 1024))[t];
  u32 sum = v.x + v.y + v.z + v.w;
#pragma unroll
  for (int off = 32; off > 0; off >>= 1) sum += __shfl_down(sum, off, 64);
  __shared__ u32 w[4];
  if ((t & 63) == 0) w[t >> 6] = sum;
  __syncthreads();
  if (t == 0) cs[blockIdx.x] = w[0] + w[1] + w[2] + w[3];
}

__global__ __launch_bounds__(256) void quantize(const float* __restrict__ x,
                                                float* __restrict__ out,
                                                const u32* __restrict__ ws,
                                                const float* __restrict__ gamma,
                                                long long n, u32 k) {
  __shared__ u32 s[256];
  __shared__ u32 r0, r1;
  __shared__ float fscale;
  const u32* g1 = ws + G1;
  const u32* cs = ws + CS;
  const u32* bc = ws + BC;
  const u32* h2 = ws + H2;
  const int t = threadIdx.x;

  // scan A: (B1, k1) -- fast path derives from bc[4]; fallback scans g1
  u32 B1, k1;
  if (ws[FLAG] == 0u) {
    const u32 below = bc[0], W0 = bc[1], W1 = bc[2];
    const u32 sub = k - below;
    if (sub < W0) {
      B1 = WIN_LO; k1 = sub;
    } else if (sub < W0 + W1) {
      B1 = WIN_LO + 1u; k1 = sub - W0;
    } else {
      B1 = WIN_LO + 2u; k1 = sub - W0 - W1;
    }
  } else {
    u32 c[8], sum = 0;
#pragma unroll
    for (int j = 0; j < 8; ++j) { c[j] = g1[t * 8 + j]; sum += c[j]; }
    s[t] = sum;
    __syncthreads();
    for (int off = 1; off < 256; off <<= 1) {
      u32 add = (t >= off) ? s[t - off] : 0u;
      __syncthreads();
      s[t] += add;
      __syncthreads();
    }
    u32 ex = s[t] - sum;
#pragma unroll
    for (int j = 0; j < 8; ++j) {
      if (k >= ex && k < ex + c[j]) { r0 = (u32)(t * 8 + j); r1 = k - ex; }
      ex += c[j];
    }
    __syncthreads();
    B1 = r0; k1 = r1;
  }
  // scan B: cs (1024 chunk sums, 4/thread) -> chunk, k2
  u32 chunk, k2;
  {
    u32 c[4], sum = 0;
#pragma unroll
    for (int j = 0; j < 4; ++j) { c[j] = cs[t * 4 + j]; sum += c[j]; }
    __syncthreads();  // protect r0/r1 reads above before rewrite below
    s[t] = sum;
    __syncthreads();
    for (int off = 1; off < 256; off <<= 1) {
      u32 add = (t >= off) ? s[t - off] : 0u;
      __syncthreads();
      s[t] += add;
      __syncthreads();
    }
    u32 ex = s[t] - sum;
#pragma unroll
    for (int j = 0; j < 4; ++j) {
      if (k1 >= ex && k1 < ex + c[j]) { r0 = (u32)(t * 4 + j); r1 = k1 - ex; }
      ex += c[j];
    }
    __syncthreads();
    chunk = r0; k2 = r1;
  }
  // scan C: h2[chunk*1024 ..] (1024 bins, 4/thread) -> exact bits -> scale
  {
    u32 c[4], sum = 0;
#pragma unroll
    for (int j = 0; j < 4; ++j) {
      c[j] = h2[(size_t)chunk * 1024 + t * 4 + j];
      sum += c[j];
    }
    __syncthreads();
    s[t] = sum;
    __syncthreads();
    for (int off = 1; off < 256; off <<= 1) {
      u32 add = (t >= off) ? s[t - off] : 0u;
      __syncthreads();
      s[t] += add;
      __syncthreads();
    }
    u32 ex = s[t] - sum;
#pragma unroll
    for (int j = 0; j < 4; ++j) {
      if (k2 >= ex && k2 < ex + c[j]) {
        const u32 bits = (B1 << 20) | (chunk * 1024u + (u32)(t * 4 + j));
        const float q = __uint_as_float(bits);
        float gm = gamma[0];
        gm = fminf(fmaxf(gm, 0.1f), 10.0f);
        fscale = (q / 127.0f) * gm;
      }
      ex += c[j];
    }
    __syncthreads();
  }
  const float scale = fscale;

  const long long n4 = n >> 2;
  const long long stride = (long long)gridDim.x * 256;
  const float4* x4 = (const float4*)x;
  nfloat4* o4 = (nfloat4*)out;
  for (long long i = (long long)blockIdx.x * 256 + t; i < n4; i += stride) {
    float4 v = x4[i];
    nfloat4 o;
    o.x = fminf(fmaxf(rintf(v.x / scale), -128.0f), 127.0f) * scale;
    o.y = fminf(fmaxf(rintf(v.y / scale), -128.0f), 127.0f) * scale;
    o.z = fminf(fmaxf(rintf(v.z / scale), -128.0f), 127.0f) * scale;
    o.w = fminf(fmaxf(rintf(v.w / scale), -128.0f), 127.0f) * scale;
    __builtin_nontemporal_store(o, &o4[i]);
  }
  for (long long i = (n4 << 2) + (long long)blockIdx.x * 256 + t; i < n;
       i += stride) {
    float v = x[i];
    out[i] = fminf(fmaxf(rintf(v / scale), -128.0f), 127.0f) * scale;
  }
}

extern "C" void kernel_launch(void* const* d_in, const int* in_sizes, int n_in,
                              void* d_out, int out_size, void* d_ws,
                              size_t ws_size, hipStream_t stream) {
  const u32* xbits = (const u32*)d_in[0];
  const float* gamma = (const float*)d_in[1];
  const long long n = (long long)in_sizes[0];
  u32* ws = (u32*)d_ws;

  const u32 k = (u32)llround(0.99 * (double)n);
  // capture needs ~12.6 MB of ws; if unavailable, force the exact slow path
  const int cap_ok = (ws_size >= NEED_U32 * sizeof(u32)) ? 1 : 0;

  (void)hipMemsetAsync(ws, 0, (size_t)ZERO_U32 * sizeof(u32), stream);
  scan_top<<<NBLK1, 256, 0, stream>>>(xbits, ws, n, cap_ok);
  resolve<<<NBLK1, 256, 0, stream>>>(xbits, ws, n, k, cap_ok ? 0 : 1);
  fallback_low<<<512, 1024, 0, stream>>>(xbits, ws, n, k);
  chunk_reduce<<<1024, 256, 0, stream>>>(ws);
  quantize<<<2048, 256, 0, stream>>>((const float*)d_in[0], (float*)d_out, ws,
                                     gamma, n, k);
}

// Round 3
// 347.493 us; speedup vs baseline: 1.3399x; 1.0247x over previous
//
#include <hip/hip_runtime.h>
#include <math.h>

typedef unsigned int u32;
typedef float nfloat4 __attribute__((ext_vector_type(4)));

// ---------------------------------------------------------------------------
// Exact 0.99-quantile of |x| via windowed speculative histogram + exact
// fallback. Lessons: R0: 33.5M LDS hist atomics = 0.73/cyc/CU bound (75us).
// R1: ballot+global-atomic-rtn capture serialized waves (244us). R2: LDS
// ds_add_rtn + dependent store still serialized (138us, 1 load/650cyc/CU).
// R9 (this): NO atomic-with-return anywhere in hot loops. scan_top streams
// x once, keeps 4 branchless register counters, and for the ~2.2% of
// elements in the window [2.25,3.0) fire-and-forgets a global atomicAdd
// into a 3x1M-bin histogram (return unused -> global_atomic_add, no
// waitcnt, no chain). That IS the level-2 histogram: no capture list, no
// resolve kernel. Window covers the N(0,1) 0.99-quantile 2.576+/-0.002
// with >30 sigma margin. Fallback (any other distribution, or small ws) is
// EXACT and isolated: always-enqueued early-exit kernels fb_top (full
// 2048-bin g1, R0's proven 8-replica LDS hist) + fb_low (full re-scan into
// H2SLOW -- separate region, so fast-path pollution of h2win is harmless).
// All producer->consumer visibility via kernel boundaries (R4/R6: fences/
// tickets regress). H2SLOW sits low so the slow path fits R0-sized ws.
//  K1 scan_top : stream x; reg-count below/window -> bc[4]; in-window ->
//                fire-and-forget atomicAdd h2win[a-LOBITS]
//  K2 fb_top   : bc valid? exit : FLAG=1, full 2048-bin hist -> g1
//  K3 fb_low   : FLAG? scan g1 -> B1, full scan -> H2SLOW : exit
//  K4 chunk_red: base = FLAG? H2SLOW : h2win+slot<<20; sum 1024-chunks -> cs
//  K5 quantize : prologue: (B1,k1) from bc (or g1 scan if FLAG), cs ->
//                (chunk,k2), base[chunk] -> exact bits -> scale; quantize x
// ws layout (u32): [0..2047] g1 | [2048..3071] cs | [3072..3075] bc |
//   [3076] FLAG | [4096..4096+1M) H2SLOW | [4096+1M .. 4096+4M) H2WIN
// ---------------------------------------------------------------------------

#define G1 0
#define CS 2048
#define BC 3072
#define FLAG 3076
#define H2S 4096
#define H2W (4096 + (1 << 20))
#define ZERO_SLOW (4096 + (1 << 20))            // slow path: headers + H2SLOW
#define ZERO_FAST (4096 + (1 << 20) + 3 * (1 << 20))  // + 3M-bin window hist
#define NBLK1 2048
// capture window: top-11 bits in [1025,1027] <=> |x| in [2.25, 3.0)
#define WIN_LO 1025u
#define WIN_HI 1027u
#define LOBITS (WIN_LO << 20)
#define SPANBITS ((WIN_HI - WIN_LO + 1u) << 20)

__global__ __launch_bounds__(256) void scan_top(const u32* __restrict__ x,
                                                u32* __restrict__ ws,
                                                long long n, int do_cap) {
  u32* bc = ws + BC;
  u32* h2w = ws + H2W;
  __shared__ u32 red[4][4];
  const int t = threadIdx.x;

  u32 bel = 0, w0 = 0, w2 = 0, tk = 0;

  const long long n4 = n >> 2;
  const long long stride = (long long)gridDim.x * 256;
  const uint4* x4 = (const uint4*)x;

  // branchless counters; only the rare fire-and-forget atomic is branchy.
#define PROC(raw)                                          \
  do {                                                     \
    const u32 a_ = (raw) & 0x7fffffffu;                    \
    const u32 d_ = a_ - LOBITS;                            \
    const bool in_ = d_ < SPANBITS;                        \
    bel += (a_ < LOBITS) ? 1u : 0u;                        \
    tk += in_ ? 1u : 0u;                                   \
    w0 += (in_ && d_ < (1u << 20)) ? 1u : 0u;              \
    w2 += (in_ && d_ >= (2u << 20)) ? 1u : 0u;             \
    if (do_cap && in_) atomicAdd(&h2w[d_], 1u);            \
  } while (0)

  for (long long i = (long long)blockIdx.x * 256 + t; i < n4; i += stride) {
    uint4 v = x4[i];
    PROC(v.x);
    PROC(v.y);
    PROC(v.z);
    PROC(v.w);
  }
  for (long long i = (n4 << 2) + (long long)blockIdx.x * 256 + t; i < n;
       i += stride)
    PROC(x[i]);
#undef PROC

#pragma unroll
  for (int off = 32; off > 0; off >>= 1) {
    bel += __shfl_down(bel, off, 64);
    w0 += __shfl_down(w0, off, 64);
    w2 += __shfl_down(w2, off, 64);
    tk += __shfl_down(tk, off, 64);
  }
  if ((t & 63) == 0) {
    const int w = t >> 6;
    red[w][0] = bel;
    red[w][1] = w0;
    red[w][2] = w2;
    red[w][3] = tk;
  }
  __syncthreads();
  if (t == 0) {
    u32 B = 0, W0 = 0, W2 = 0, TK = 0;
#pragma unroll
    for (int w = 0; w < 4; ++w) {
      B += red[w][0];
      W0 += red[w][1];
      W2 += red[w][2];
      TK += red[w][3];
    }
    if (B) atomicAdd(&bc[0], B);
    if (W0) atomicAdd(&bc[1], W0);
    const u32 W1 = TK - W0 - W2;
    if (W1) atomicAdd(&bc[2], W1);
    if (W2) atomicAdd(&bc[3], W2);
  }
}

// Always enqueued. Fast path: uniform early exit (~2us). Bad path: set FLAG,
// build the full 2048-bin g1 (R0's proven 8-replica LDS histogram).
__global__ __launch_bounds__(1024) void fb_top(const u32* __restrict__ x,
                                               u32* __restrict__ ws,
                                               long long n, u32 k, int force) {
  __shared__ u32 h[2048 * 8];  // 64 KB (allocated either way; kernel is a
                               // no-op on the fast path so it doesn't matter)
  __shared__ int bad;
  const int t = threadIdx.x;
  if (t == 0) {
    bad = force;
    if (!force) {
      const u32 below = ws[BC], W0 = ws[BC + 1], W1 = ws[BC + 2],
                W2 = ws[BC + 3];
      if (k < below || (k - below) >= W0 + W1 + W2) bad = 1;
    }
  }
  __syncthreads();
  if (!bad) return;  // block-uniform
  if (t == 0) ws[FLAG] = 1u;  // all blocks write 1 -- benign

  u32* g1 = ws + G1;
  for (int i = t; i < 2048 * 8; i += 1024) h[i] = 0;
  __syncthreads();
  const u32 r = (u32)(t & 7);
  const long long n4 = n >> 2;
  const long long stride = (long long)gridDim.x * 1024;
  const uint4* x4 = (const uint4*)x;
  for (long long i = (long long)blockIdx.x * 1024 + t; i < n4; i += stride) {
    uint4 v = x4[i];
    atomicAdd(&h[(((v.x & 0x7fffffffu) >> 20) << 3) + r], 1u);
    atomicAdd(&h[(((v.y & 0x7fffffffu) >> 20) << 3) + r], 1u);
    atomicAdd(&h[(((v.z & 0x7fffffffu) >> 20) << 3) + r], 1u);
    atomicAdd(&h[(((v.w & 0x7fffffffu) >> 20) << 3) + r], 1u);
  }
  for (long long i = (n4 << 2) + (long long)blockIdx.x * 1024 + t; i < n;
       i += stride)
    atomicAdd(&h[(((x[i] & 0x7fffffffu) >> 20) << 3) + r], 1u);
  __syncthreads();
  for (int i = t; i < 2048; i += 1024) {
    u32 c = 0;
#pragma unroll
    for (int j = 0; j < 8; ++j) c += h[(i << 3) + j];
    if (c) atomicAdd(&g1[i], c);
  }
}

// Always enqueued; no-op unless FLAG (exact fallback: original hist_low,
// writing the dedicated H2SLOW region).
__global__ __launch_bounds__(1024) void fb_low(const u32* __restrict__ x,
                                               u32* __restrict__ ws,
                                               long long n, u32 k) {
  __shared__ u32 s[1024];
  __shared__ u32 resB1;
  if (ws[FLAG] == 0u) return;  // uniform

  const u32* g1 = ws + G1;
  u32* h2 = ws + H2S;
  const int t = threadIdx.x;
  {
    const uint2 c2 = ((const uint2*)g1)[t];
    const u32 sum = c2.x + c2.y;
    s[t] = sum;
    __syncthreads();
    for (int off = 1; off < 1024; off <<= 1) {
      u32 add = (t >= off) ? s[t - off] : 0u;
      __syncthreads();
      s[t] += add;
      __syncthreads();
    }
    u32 ex = s[t] - sum;
    if (k >= ex && k < ex + c2.x) resB1 = 2 * t;
    ex += c2.x;
    if (k >= ex && k < ex + c2.y) resB1 = 2 * t + 1;
    __syncthreads();
  }
  const u32 B1 = resB1;

  const long long n4 = n >> 2;
  const long long stride = (long long)gridDim.x * 1024;
  const uint4* x4 = (const uint4*)x;
  for (long long i = (long long)blockIdx.x * 1024 + t; i < n4; i += stride) {
    uint4 v = x4[i];
    u32 a;
    a = v.x & 0x7fffffffu; if ((a >> 20) == B1) atomicAdd(&h2[a & 0xFFFFFu], 1u);
    a = v.y & 0x7fffffffu; if ((a >> 20) == B1) atomicAdd(&h2[a & 0xFFFFFu], 1u);
    a = v.z & 0x7fffffffu; if ((a >> 20) == B1) atomicAdd(&h2[a & 0xFFFFFu], 1u);
    a = v.w & 0x7fffffffu; if ((a >> 20) == B1) atomicAdd(&h2[a & 0xFFFFFu], 1u);
  }
  for (long long i = (n4 << 2) + (long long)blockIdx.x * 1024 + t; i < n;
       i += stride) {
    const u32 a = x[i] & 0x7fffffffu;
    if ((a >> 20) == B1) atomicAdd(&h2[a & 0xFFFFFu], 1u);
  }
}

// 1024 blocks: block b sums base[b*1024 .. b*1024+1024) -> cs[b].
// base chosen redundantly from L2-hot FLAG/bc (block-uniform).
__global__ __launch_bounds__(256) void chunk_reduce(u32* __restrict__ ws,
                                                    u32 k) {
  const int t = threadIdx.x;
  const u32* base;
  if (ws[FLAG] != 0u) {
    base = ws + H2S;
  } else {
    const u32 below = ws[BC], W0 = ws[BC + 1], W1 = ws[BC + 2];
    const u32 sub = k - below;
    const u32 slot = (sub < W0) ? 0u : ((sub < W0 + W1) ? 1u : 2u);
    base = ws + H2W + ((size_t)slot << 20);
  }
  u32* cs = ws + CS;
  uint4 v = ((const uint4*)(base + (size_t)blockIdx.x * 1024))[t];
  u32 sum = v.x + v.y + v.z + v.w;
#pragma unroll
  for (int off = 32; off > 0; off >>= 1) sum += __shfl_down(sum, off, 64);
  __shared__ u32 w[4];
  if ((t & 63) == 0) w[t >> 6] = sum;
  __syncthreads();
  if (t == 0) cs[blockIdx.x] = w[0] + w[1] + w[2] + w[3];
}

__global__ __launch_bounds__(256) void quantize(const float* __restrict__ x,
                                                float* __restrict__ out,
                                                const u32* __restrict__ ws,
                                                const float* __restrict__ gamma,
                                                long long n, u32 k) {
  __shared__ u32 s[256];
  __shared__ u32 r0, r1;
  __shared__ float fscale;
  const u32* g1 = ws + G1;
  const u32* cs = ws + CS;
  const int t = threadIdx.x;
  const int flag = (ws[FLAG] != 0u);

  // scan A: (B1, k1) -- fast path derives from bc[4]; fallback scans g1
  u32 B1, k1;
  const u32* h2base;
  if (!flag) {
    const u32 below = ws[BC], W0 = ws[BC + 1], W1 = ws[BC + 2];
    const u32 sub = k - below;
    u32 slot;
    if (sub < W0) {
      slot = 0u; k1 = sub;
    } else if (sub < W0 + W1) {
      slot = 1u; k1 = sub - W0;
    } else {
      slot = 2u; k1 = sub - W0 - W1;
    }
    B1 = WIN_LO + slot;
    h2base = ws + H2W + ((size_t)slot << 20);
  } else {
    u32 c[8], sum = 0;
#pragma unroll
    for (int j = 0; j < 8; ++j) { c[j] = g1[t * 8 + j]; sum += c[j]; }
    s[t] = sum;
    __syncthreads();
    for (int off = 1; off < 256; off <<= 1) {
      u32 add = (t >= off) ? s[t - off] : 0u;
      __syncthreads();
      s[t] += add;
      __syncthreads();
    }
    u32 ex = s[t] - sum;
#pragma unroll
    for (int j = 0; j < 8; ++j) {
      if (k >= ex && k < ex + c[j]) { r0 = (u32)(t * 8 + j); r1 = k - ex; }
      ex += c[j];
    }
    __syncthreads();
    B1 = r0; k1 = r1;
    h2base = ws + H2S;
  }
  // scan B: cs (1024 chunk sums, 4/thread) -> chunk, k2
  u32 chunk, k2;
  {
    u32 c[4], sum = 0;
#pragma unroll
    for (int j = 0; j < 4; ++j) { c[j] = cs[t * 4 + j]; sum += c[j]; }
    __syncthreads();  // protect r0/r1 reads above before rewrite below
    s[t] = sum;
    __syncthreads();
    for (int off = 1; off < 256; off <<= 1) {
      u32 add = (t >= off) ? s[t - off] : 0u;
      __syncthreads();
      s[t] += add;
      __syncthreads();
    }
    u32 ex = s[t] - sum;
#pragma unroll
    for (int j = 0; j < 4; ++j) {
      if (k1 >= ex && k1 < ex + c[j]) { r0 = (u32)(t * 4 + j); r1 = k1 - ex; }
      ex += c[j];
    }
    __syncthreads();
    chunk = r0; k2 = r1;
  }
  // scan C: h2base[chunk*1024 ..] (1024 bins, 4/thread) -> bits -> scale
  {
    u32 c[4], sum = 0;
#pragma unroll
    for (int j = 0; j < 4; ++j) {
      c[j] = h2base[(size_t)chunk * 1024 + t * 4 + j];
      sum += c[j];
    }
    __syncthreads();
    s[t] = sum;
    __syncthreads();
    for (int off = 1; off < 256; off <<= 1) {
      u32 add = (t >= off) ? s[t - off] : 0u;
      __syncthreads();
      s[t] += add;
      __syncthreads();
    }
    u32 ex = s[t] - sum;
#pragma unroll
    for (int j = 0; j < 4; ++j) {
      if (k2 >= ex && k2 < ex + c[j]) {
        const u32 bits = (B1 << 20) | (chunk * 1024u + (u32)(t * 4 + j));
        const float q = __uint_as_float(bits);
        float gm = gamma[0];
        gm = fminf(fmaxf(gm, 0.1f), 10.0f);
        fscale = (q / 127.0f) * gm;
      }
      ex += c[j];
    }
    __syncthreads();
  }
  const float scale = fscale;

  const long long n4 = n >> 2;
  const long long stride = (long long)gridDim.x * 256;
  const float4* x4 = (const float4*)x;
  nfloat4* o4 = (nfloat4*)out;
  for (long long i = (long long)blockIdx.x * 256 + t; i < n4; i += stride) {
    float4 v = x4[i];
    nfloat4 o;
    o.x = fminf(fmaxf(rintf(v.x / scale), -128.0f), 127.0f) * scale;
    o.y = fminf(fmaxf(rintf(v.y / scale), -128.0f), 127.0f) * scale;
    o.z = fminf(fmaxf(rintf(v.z / scale), -128.0f), 127.0f) * scale;
    o.w = fminf(fmaxf(rintf(v.w / scale), -128.0f), 127.0f) * scale;
    __builtin_nontemporal_store(o, &o4[i]);
  }
  for (long long i = (n4 << 2) + (long long)blockIdx.x * 256 + t; i < n;
       i += stride) {
    float v = x[i];
    out[i] = fminf(fmaxf(rintf(v / scale), -128.0f), 127.0f) * scale;
  }
}

extern "C" void kernel_launch(void* const* d_in, const int* in_sizes, int n_in,
                              void* d_out, int out_size, void* d_ws,
                              size_t ws_size, hipStream_t stream) {
  const u32* xbits = (const u32*)d_in[0];
  const float* gamma = (const float*)d_in[1];
  const long long n = (long long)in_sizes[0];
  u32* ws = (u32*)d_ws;

  const u32 k = (u32)llround(0.99 * (double)n);
  // fast path needs 16.8 MB of ws (3M-bin window hist); else exact slow path
  const int cap_ok = (ws_size >= (size_t)ZERO_FAST * sizeof(u32)) ? 1 : 0;
  const size_t zero_u32 = cap_ok ? (size_t)ZERO_FAST : (size_t)ZERO_SLOW;

  (void)hipMemsetAsync(ws, 0, zero_u32 * sizeof(u32), stream);
  scan_top<<<NBLK1, 256, 0, stream>>>(xbits, ws, n, cap_ok);
  fb_top<<<512, 1024, 0, stream>>>(xbits, ws, n, k, cap_ok ? 0 : 1);
  fb_low<<<512, 1024, 0, stream>>>(xbits, ws, n, k);
  chunk_reduce<<<1024, 256, 0, stream>>>(ws, k);
  quantize<<<2048, 256, 0, stream>>>((const float*)d_in[0], (float*)d_out, ws,
                                     gamma, n, k);
}

// Round 4
// 274.008 us; speedup vs baseline: 1.6992x; 1.2682x over previous
//
#include <hip/hip_runtime.h>
#include <math.h>

typedef unsigned int u32;
typedef float nfloat4 __attribute__((ext_vector_type(4)));

// ---------------------------------------------------------------------------
// Exact 0.99-quantile of |x| via windowed speculative histogram + exact
// fallback. Ladder: R0 75us/pass (LDS-atomic bound, 1024-thr blocks).
// R1 244us (ballot+rtn chain). R2 138 / R3 130 (256-thr blocks: occupancy
// 45-54% -- pass rate tracks GEOMETRY not inner work; 1024-thr blocks hit
// 84%). R10 (this): both full-pass kernels at 512x1024 + manual unroll for
// intra-wave MLP (scan: 4 loads in flight; quantize: 2+2). Inner bodies
// unchanged from R3: branchless counters + fire-and-forget global atomic
// into 3x1M-bin window hist for the ~2.2% of elems in [2.25,3.0) (covers
// N(0,1) q99=2.576 +/- 0.002 at >30 sigma). Fallback (any other dist, or
// small ws) EXACT via always-enqueued early-exit kernels fb_top (full
// 2048-bin g1) + fb_low (full re-scan -> H2SLOW, isolated from fast-path
// pollution). All visibility via kernel boundaries (R4/R6: fences regress).
//  K1 scan_top : stream x (4 uint4/iter); counters -> bc[4]; in-window ->
//                fire-and-forget atomicAdd h2win[a-LOBITS]
//  K2 fb_top   : bc valid? exit : FLAG=1, full 2048-bin hist -> g1
//  K3 fb_low   : FLAG? scan g1 -> B1, full scan -> H2SLOW : exit
//  K4 chunk_red: base = FLAG? H2SLOW : h2win+slot<<20; 1024-chunk sums -> cs
//  K5 quantize : prologue (1024-wide scans): (B1,k1) from bc (or g1 if
//                FLAG), cs -> (chunk,k2), base[chunk] -> bits -> scale;
//                then fake-quantize (2 uint4/iter)
// ws layout (u32): [0..2047] g1 | [2048..3071] cs | [3072..3075] bc |
//   [3076] FLAG | [4096..4096+1M) H2SLOW | [4096+1M .. 4096+4M) H2WIN
// ---------------------------------------------------------------------------

#define G1 0
#define CS 2048
#define BC 3072
#define FLAG 3076
#define H2S 4096
#define H2W (4096 + (1 << 20))
#define ZERO_SLOW (4096 + (1 << 20))
#define ZERO_FAST (4096 + (1 << 20) + 3 * (1 << 20))
#define WIN_LO 1025u
#define WIN_HI 1027u
#define LOBITS (WIN_LO << 20)
#define SPANBITS ((WIN_HI - WIN_LO + 1u) << 20)

__global__ __launch_bounds__(1024) void scan_top(const u32* __restrict__ x,
                                                 u32* __restrict__ ws,
                                                 long long n, int do_cap) {
  u32* bc = ws + BC;
  u32* h2w = ws + H2W;
  __shared__ u32 red[16][4];
  const int t = threadIdx.x;

  u32 bel = 0, w0 = 0, w2 = 0, tk = 0;

  const long long n4 = n >> 2;
  const uint4* x4 = (const uint4*)x;

#define PROC(raw)                                          \
  do {                                                     \
    const u32 a_ = (raw) & 0x7fffffffu;                    \
    const u32 d_ = a_ - LOBITS;                            \
    const bool in_ = d_ < SPANBITS;                        \
    bel += (a_ < LOBITS) ? 1u : 0u;                        \
    tk += in_ ? 1u : 0u;                                   \
    w0 += (in_ && d_ < (1u << 20)) ? 1u : 0u;              \
    w2 += (in_ && d_ >= (2u << 20)) ? 1u : 0u;             \
    if (do_cap && in_) atomicAdd(&h2w[d_], 1u);            \
  } while (0)
#define PROC4(v) do { PROC((v).x); PROC((v).y); PROC((v).z); PROC((v).w); } while (0)

  // main: 4 uint4 loads in flight per iteration (block chunk = 4096 uint4)
  const long long CH = (long long)gridDim.x * 4096;
  long long i = (long long)blockIdx.x * 4096 + t;
  for (; i + 3072 < n4; i += CH) {
    uint4 va = x4[i];
    uint4 vb = x4[i + 1024];
    uint4 vc = x4[i + 2048];
    uint4 vd = x4[i + 3072];
    PROC4(va);
    PROC4(vb);
    PROC4(vc);
    PROC4(vd);
  }
  for (int q = 0; q < 3; ++q, i += 1024)
    if (i < n4) {
      uint4 v = x4[i];
      PROC4(v);
    }
  for (long long j = (n4 << 2) + (long long)blockIdx.x * 1024 + t; j < n;
       j += (long long)gridDim.x * 1024)
    PROC(x[j]);
#undef PROC4
#undef PROC

#pragma unroll
  for (int off = 32; off > 0; off >>= 1) {
    bel += __shfl_down(bel, off, 64);
    w0 += __shfl_down(w0, off, 64);
    w2 += __shfl_down(w2, off, 64);
    tk += __shfl_down(tk, off, 64);
  }
  if ((t & 63) == 0) {
    const int w = t >> 6;
    red[w][0] = bel;
    red[w][1] = w0;
    red[w][2] = w2;
    red[w][3] = tk;
  }
  __syncthreads();
  if (t == 0) {
    u32 B = 0, W0 = 0, W2 = 0, TK = 0;
#pragma unroll
    for (int w = 0; w < 16; ++w) {
      B += red[w][0];
      W0 += red[w][1];
      W2 += red[w][2];
      TK += red[w][3];
    }
    if (B) atomicAdd(&bc[0], B);
    if (W0) atomicAdd(&bc[1], W0);
    const u32 W1 = TK - W0 - W2;
    if (W1) atomicAdd(&bc[2], W1);
    if (W2) atomicAdd(&bc[3], W2);
  }
}

// Always enqueued. Fast path: uniform early exit. Bad path: set FLAG, build
// the full 2048-bin g1 (R0's proven 8-replica LDS histogram).
__global__ __launch_bounds__(1024) void fb_top(const u32* __restrict__ x,
                                               u32* __restrict__ ws,
                                               long long n, u32 k, int force) {
  __shared__ u32 h[2048 * 8];  // 64 KB; kernel is a no-op on the fast path
  __shared__ int bad;
  const int t = threadIdx.x;
  if (t == 0) {
    bad = force;
    if (!force) {
      const u32 below = ws[BC], W0 = ws[BC + 1], W1 = ws[BC + 2],
                W2 = ws[BC + 3];
      if (k < below || (k - below) >= W0 + W1 + W2) bad = 1;
    }
  }
  __syncthreads();
  if (!bad) return;  // block-uniform
  if (t == 0) ws[FLAG] = 1u;  // all blocks write 1 -- benign

  u32* g1 = ws + G1;
  for (int i = t; i < 2048 * 8; i += 1024) h[i] = 0;
  __syncthreads();
  const u32 r = (u32)(t & 7);
  const long long n4 = n >> 2;
  const long long stride = (long long)gridDim.x * 1024;
  const uint4* x4 = (const uint4*)x;
  for (long long i = (long long)blockIdx.x * 1024 + t; i < n4; i += stride) {
    uint4 v = x4[i];
    atomicAdd(&h[(((v.x & 0x7fffffffu) >> 20) << 3) + r], 1u);
    atomicAdd(&h[(((v.y & 0x7fffffffu) >> 20) << 3) + r], 1u);
    atomicAdd(&h[(((v.z & 0x7fffffffu) >> 20) << 3) + r], 1u);
    atomicAdd(&h[(((v.w & 0x7fffffffu) >> 20) << 3) + r], 1u);
  }
  for (long long i = (n4 << 2) + (long long)blockIdx.x * 1024 + t; i < n;
       i += stride)
    atomicAdd(&h[(((x[i] & 0x7fffffffu) >> 20) << 3) + r], 1u);
  __syncthreads();
  for (int i = t; i < 2048; i += 1024) {
    u32 c = 0;
#pragma unroll
    for (int j = 0; j < 8; ++j) c += h[(i << 3) + j];
    if (c) atomicAdd(&g1[i], c);
  }
}

// Always enqueued; no-op unless FLAG (exact fallback: original hist_low,
// writing the dedicated H2SLOW region).
__global__ __launch_bounds__(1024) void fb_low(const u32* __restrict__ x,
                                               u32* __restrict__ ws,
                                               long long n, u32 k) {
  __shared__ u32 s[1024];
  __shared__ u32 resB1;
  if (ws[FLAG] == 0u) return;  // uniform

  const u32* g1 = ws + G1;
  u32* h2 = ws + H2S;
  const int t = threadIdx.x;
  {
    const uint2 c2 = ((const uint2*)g1)[t];
    const u32 sum = c2.x + c2.y;
    s[t] = sum;
    __syncthreads();
    for (int off = 1; off < 1024; off <<= 1) {
      u32 add = (t >= off) ? s[t - off] : 0u;
      __syncthreads();
      s[t] += add;
      __syncthreads();
    }
    u32 ex = s[t] - sum;
    if (k >= ex && k < ex + c2.x) resB1 = 2 * t;
    ex += c2.x;
    if (k >= ex && k < ex + c2.y) resB1 = 2 * t + 1;
    __syncthreads();
  }
  const u32 B1 = resB1;

  const long long n4 = n >> 2;
  const long long stride = (long long)gridDim.x * 1024;
  const uint4* x4 = (const uint4*)x;
  for (long long i = (long long)blockIdx.x * 1024 + t; i < n4; i += stride) {
    uint4 v = x4[i];
    u32 a;
    a = v.x & 0x7fffffffu; if ((a >> 20) == B1) atomicAdd(&h2[a & 0xFFFFFu], 1u);
    a = v.y & 0x7fffffffu; if ((a >> 20) == B1) atomicAdd(&h2[a & 0xFFFFFu], 1u);
    a = v.z & 0x7fffffffu; if ((a >> 20) == B1) atomicAdd(&h2[a & 0xFFFFFu], 1u);
    a = v.w & 0x7fffffffu; if ((a >> 20) == B1) atomicAdd(&h2[a & 0xFFFFFu], 1u);
  }
  for (long long i = (n4 << 2) + (long long)blockIdx.x * 1024 + t; i < n;
       i += stride) {
    const u32 a = x[i] & 0x7fffffffu;
    if ((a >> 20) == B1) atomicAdd(&h2[a & 0xFFFFFu], 1u);
  }
}

// 1024 blocks: block b sums base[b*1024 .. b*1024+1024) -> cs[b].
__global__ __launch_bounds__(256) void chunk_reduce(u32* __restrict__ ws,
                                                    u32 k) {
  const int t = threadIdx.x;
  const u32* base;
  if (ws[FLAG] != 0u) {
    base = ws + H2S;
  } else {
    const u32 below = ws[BC], W0 = ws[BC + 1], W1 = ws[BC + 2];
    const u32 sub = k - below;
    const u32 slot = (sub < W0) ? 0u : ((sub < W0 + W1) ? 1u : 2u);
    base = ws + H2W + ((size_t)slot << 20);
  }
  u32* cs = ws + CS;
  uint4 v = ((const uint4*)(base + (size_t)blockIdx.x * 1024))[t];
  u32 sum = v.x + v.y + v.z + v.w;
#pragma unroll
  for (int off = 32; off > 0; off >>= 1) sum += __shfl_down(sum, off, 64);
  __shared__ u32 w[4];
  if ((t & 63) == 0) w[t >> 6] = sum;
  __syncthreads();
  if (t == 0) cs[blockIdx.x] = w[0] + w[1] + w[2] + w[3];
}

__global__ __launch_bounds__(1024) void quantize(const float* __restrict__ x,
                                                 float* __restrict__ out,
                                                 const u32* __restrict__ ws,
                                                 const float* __restrict__ gamma,
                                                 long long n, u32 k) {
  __shared__ u32 s[1024];
  __shared__ u32 r0, r1;
  __shared__ float fscale;
  const u32* cs = ws + CS;
  const int t = threadIdx.x;
  const int flag = (ws[FLAG] != 0u);

  // scan A: (B1, k1) -- fast path from bc[4]; fallback: 1024-wide g1 scan
  u32 B1, k1;
  const u32* h2base;
  if (!flag) {
    const u32 below = ws[BC], W0 = ws[BC + 1], W1 = ws[BC + 2];
    const u32 sub = k - below;
    u32 slot;
    if (sub < W0) {
      slot = 0u; k1 = sub;
    } else if (sub < W0 + W1) {
      slot = 1u; k1 = sub - W0;
    } else {
      slot = 2u; k1 = sub - W0 - W1;
    }
    B1 = WIN_LO + slot;
    h2base = ws + H2W + ((size_t)slot << 20);
  } else {
    const uint2 c2 = ((const uint2*)(ws + G1))[t];
    const u32 sum = c2.x + c2.y;
    s[t] = sum;
    __syncthreads();
    for (int off = 1; off < 1024; off <<= 1) {
      u32 add = (t >= off) ? s[t - off] : 0u;
      __syncthreads();
      s[t] += add;
      __syncthreads();
    }
    u32 ex = s[t] - sum;
    if (k >= ex && k < ex + c2.x) { r0 = 2u * t; r1 = k - ex; }
    ex += c2.x;
    if (k >= ex && k < ex + c2.y) { r0 = 2u * t + 1u; r1 = k - ex; }
    __syncthreads();
    B1 = r0; k1 = r1;
    h2base = ws + H2S;
  }
  // scan B: cs (1024 chunk sums, 1/thread) -> chunk, k2
  u32 chunk, k2;
  {
    const u32 c = cs[t];
    __syncthreads();  // separates any scan-A s[] reads from rewrite
    s[t] = c;
    __syncthreads();
    for (int off = 1; off < 1024; off <<= 1) {
      u32 add = (t >= off) ? s[t - off] : 0u;
      __syncthreads();
      s[t] += add;
      __syncthreads();
    }
    u32 ex = s[t] - c;
    if (k1 >= ex && k1 < ex + c) { r0 = (u32)t; r1 = k1 - ex; }
    __syncthreads();
    chunk = r0; k2 = r1;
  }
  // scan C: h2base[chunk*1024 + t] -> exact bits -> scale
  {
    const u32 c = h2base[(size_t)chunk * 1024 + t];
    __syncthreads();
    s[t] = c;
    __syncthreads();
    for (int off = 1; off < 1024; off <<= 1) {
      u32 add = (t >= off) ? s[t - off] : 0u;
      __syncthreads();
      s[t] += add;
      __syncthreads();
    }
    u32 ex = s[t] - c;
    if (k2 >= ex && k2 < ex + c) {
      const u32 bits = (B1 << 20) | (chunk * 1024u + (u32)t);
      const float q = __uint_as_float(bits);
      float gm = gamma[0];
      gm = fminf(fmaxf(gm, 0.1f), 10.0f);
      fscale = (q / 127.0f) * gm;
    }
    __syncthreads();
  }
  const float scale = fscale;

  // hot loop: 2 loads + 2 stores in flight per iteration
  const long long n4 = n >> 2;
  const float4* x4 = (const float4*)x;
  nfloat4* o4 = (nfloat4*)out;
#define QUANT(v, o)                                              \
  do {                                                           \
    (o).x = fminf(fmaxf(rintf((v).x / scale), -128.0f), 127.0f) * scale; \
    (o).y = fminf(fmaxf(rintf((v).y / scale), -128.0f), 127.0f) * scale; \
    (o).z = fminf(fmaxf(rintf((v).z / scale), -128.0f), 127.0f) * scale; \
    (o).w = fminf(fmaxf(rintf((v).w / scale), -128.0f), 127.0f) * scale; \
  } while (0)

  const long long CH = (long long)gridDim.x * 2048;
  long long i = (long long)blockIdx.x * 2048 + t;
  for (; i + 1024 < n4; i += CH) {
    float4 va = x4[i];
    float4 vb = x4[i + 1024];
    nfloat4 oa, ob;
    QUANT(va, oa);
    QUANT(vb, ob);
    __builtin_nontemporal_store(oa, &o4[i]);
    __builtin_nontemporal_store(ob, &o4[i + 1024]);
  }
  if (i < n4) {
    float4 v = x4[i];
    nfloat4 o;
    QUANT(v, o);
    __builtin_nontemporal_store(o, &o4[i]);
  }
#undef QUANT
  for (long long j = (n4 << 2) + (long long)blockIdx.x * 1024 + t; j < n;
       j += (long long)gridDim.x * 1024) {
    float v = x[j];
    out[j] = fminf(fmaxf(rintf(v / scale), -128.0f), 127.0f) * scale;
  }
}

extern "C" void kernel_launch(void* const* d_in, const int* in_sizes, int n_in,
                              void* d_out, int out_size, void* d_ws,
                              size_t ws_size, hipStream_t stream) {
  const u32* xbits = (const u32*)d_in[0];
  const float* gamma = (const float*)d_in[1];
  const long long n = (long long)in_sizes[0];
  u32* ws = (u32*)d_ws;

  const u32 k = (u32)llround(0.99 * (double)n);
  const int cap_ok = (ws_size >= (size_t)ZERO_FAST * sizeof(u32)) ? 1 : 0;
  const size_t zero_u32 = cap_ok ? (size_t)ZERO_FAST : (size_t)ZERO_SLOW;

  (void)hipMemsetAsync(ws, 0, zero_u32 * sizeof(u32), stream);
  scan_top<<<512, 1024, 0, stream>>>(xbits, ws, n, cap_ok);
  fb_top<<<512, 1024, 0, stream>>>(xbits, ws, n, k, cap_ok ? 0 : 1);
  fb_low<<<512, 1024, 0, stream>>>(xbits, ws, n, k);
  chunk_reduce<<<1024, 256, 0, stream>>>(ws, k);
  quantize<<<512, 1024, 0, stream>>>((const float*)d_in[0], (float*)d_out, ws,
                                     gamma, n, k);
}